// Round 1
// baseline (446.438 us; speedup 1.0000x reference)
//
#include <hip/hip_runtime.h>
#include <cstdint>
#include <cstddef>

// CompressiveMemory: B=2,H=32,T=4096,D=128 fp32.
// out  = phi(Q)@M / max(phi(Q)@z, eps)      (per b,h)
// Mnew = M + sum_t phiKb(t) outer Vb(t)     (b-mean inside phi for K)
// znew = z + sum_t phiKb(t)

typedef __bf16 bf16x8 __attribute__((ext_vector_type(8)));
typedef float  f32x4  __attribute__((ext_vector_type(4)));
typedef unsigned short us4v __attribute__((ext_vector_type(4)));
typedef unsigned short us8v __attribute__((ext_vector_type(8)));

#define NB 2
#define NH 32
#define NT 4096
#define ND 128
#define NC 16          // split-K chunks for the update GEMM
#define TCH (NT / NC)  // 256 t-rows per chunk
#define EPSF 1e-6f

__device__ __forceinline__ float phi_f(float x) {
    // elu(x)+1 : x>0 -> x+1 ; x<=0 -> exp(x)
    return x > 0.0f ? x + 1.0f : __expf(x);
}

__device__ __forceinline__ unsigned short f2bf(float f) {
    union { float f; unsigned u; } c; c.f = f;
    unsigned r = c.u + 0x7FFFu + ((c.u >> 16) & 1u);  // RNE
    return (unsigned short)(r >> 16);
}

// ---------------------------------------------------------------- k_prep
// Mt[h][e][d] = bf16(M[h][d][e])  (transposed so MFMA B-operand rows are
// k-contiguous). 524288 elements; M is 2MB -> L2-resident, gather is cheap.
__global__ __launch_bounds__(256) void k_prep(const float* __restrict__ M,
                                              unsigned short* __restrict__ Mt) {
    int idx = blockIdx.x * 256 + threadIdx.x;        // < 32*128*128
    int h = idx >> 14, rem = idx & 16383;
    int e = rem >> 7, d = rem & 127;
    Mt[idx] = f2bf(M[(h << 14) + (d << 7) + e]);
}

// ---------------------------------------------------------------- k_out
// grid = 64 (b,h) * 32 t-tiles = 2048 blocks, 256 threads (4 waves).
// Per block: C(128x128) = phiQ(128x128) @ M(128x128), then /norm.
__global__ __launch_bounds__(256) void k_out(const float* __restrict__ Q,
                                             const unsigned short* __restrict__ Mt,
                                             const float* __restrict__ z,
                                             float* __restrict__ out) {
    __shared__ unsigned short As[128 * 136];  // phiQ  [t][d], stride 136 (16B-aligned rows)
    __shared__ unsigned short Bs[128 * 136];  // M^T   [e][d]
    __shared__ float nrm[128];

    const int tid  = threadIdx.x;
    const int tile = blockIdx.x & 31;
    const int bh   = blockIdx.x >> 5;  // b*32+h
    const int h    = bh & 31;
    const float* Qb = Q + ((size_t)bh * NT + (size_t)tile * 128) * ND;

    // --- stage Mt -> Bs (coalesced 16B copies) ---
    {
        const us8v* src = (const us8v*)(Mt + (size_t)h * 128 * 128);
#pragma unroll
        for (int i = 0; i < 8; ++i) {
            int idx = i * 256 + tid;       // 16B-chunk id (2048 total)
            int e  = idx >> 4;
            int d8 = (idx & 15) << 3;
            us8v v = src[idx];
            *(us8v*)&Bs[e * 136 + d8] = v;
        }
    }
    // --- stage phi(Q) -> As, fold norm = phiQ . z on the fly ---
    {
        const int d0 = (tid & 31) << 2;   // fixed d-quad per thread
        const int rb = tid >> 5;          // row base 0..7
        const float4 zv = *(const float4*)(z + h * ND + d0);
#pragma unroll
        for (int i = 0; i < 16; ++i) {
            int r = rb + i * 8;
            float4 q = *(const float4*)(Qb + (size_t)r * ND + d0);
            float p0 = phi_f(q.x), p1 = phi_f(q.y), p2 = phi_f(q.z), p3 = phi_f(q.w);
            float part = p0 * zv.x + p1 * zv.y + p2 * zv.z + p3 * zv.w;
            part += __shfl_xor(part, 1);
            part += __shfl_xor(part, 2);
            part += __shfl_xor(part, 4);
            part += __shfl_xor(part, 8);
            part += __shfl_xor(part, 16);   // half-wave (32-lane) reduce
            if ((tid & 31) == 0) nrm[r] = part;
            us4v pk;
            pk.x = f2bf(p0); pk.y = f2bf(p1); pk.z = f2bf(p2); pk.w = f2bf(p3);
            *(us4v*)&As[r * 136 + d0] = pk;
        }
    }
    __syncthreads();

    const int lane = tid & 63, wave = tid >> 6;
    const int mw = (wave & 1) << 6, nw = (wave >> 1) << 6;  // 64x64 per wave
    const int l15 = lane & 15, qd = lane >> 4;

    f32x4 acc[4][4];
#pragma unroll
    for (int a = 0; a < 4; ++a)
#pragma unroll
        for (int b = 0; b < 4; ++b) acc[a][b] = (f32x4){0.f, 0.f, 0.f, 0.f};

#pragma unroll
    for (int kk = 0; kk < 4; ++kk) {
        const int k0 = kk * 32 + qd * 8;
        bf16x8 af[4], bfv[4];
#pragma unroll
        for (int im = 0; im < 4; ++im)
            af[im] = *(const bf16x8*)&As[(mw + im * 16 + l15) * 136 + k0];
#pragma unroll
        for (int in = 0; in < 4; ++in)
            bfv[in] = *(const bf16x8*)&Bs[(nw + in * 16 + l15) * 136 + k0];
#pragma unroll
        for (int im = 0; im < 4; ++im)
#pragma unroll
            for (int in = 0; in < 4; ++in)
                acc[im][in] = __builtin_amdgcn_mfma_f32_16x16x32_bf16(
                    af[im], bfv[in], acc[im][in], 0, 0, 0);
    }

    float inv[4][4];
#pragma unroll
    for (int im = 0; im < 4; ++im)
#pragma unroll
        for (int rg = 0; rg < 4; ++rg)
            inv[im][rg] = 1.0f / fmaxf(nrm[mw + im * 16 + qd * 4 + rg], EPSF);

    float* outb = out + ((size_t)bh * NT + (size_t)tile * 128) * ND;
#pragma unroll
    for (int im = 0; im < 4; ++im)
#pragma unroll
        for (int in = 0; in < 4; ++in) {
            int col = nw + in * 16 + l15;
#pragma unroll
            for (int rg = 0; rg < 4; ++rg) {
                int row = mw + im * 16 + qd * 4 + rg;
                outb[(size_t)row * ND + col] = acc[im][in][rg] * inv[im][rg];
            }
        }
}

// ---------------------------------------------------------------- k_upd
// grid = 32 h * NC chunks = 512 blocks. Each block: partial
// C[d][e] = sum_{t in chunk} phiKb[t][d] * Vb[t][e]  (128x128, MFMA, k=t)
// plus zpart[d] = sum_t phiKb[t][d]. Deterministic partials to workspace.
__global__ __launch_bounds__(256) void k_upd(const float* __restrict__ K,
                                             const float* __restrict__ V,
                                             float* __restrict__ part,
                                             float* __restrict__ zpart) {
    __shared__ unsigned short Kl[128 * 72];  // phiKb [d][t], stride 72
    __shared__ unsigned short Vl[128 * 72];  // Vb    [e][t]
    __shared__ float zacc[128];

    const int tid = threadIdx.x;
    const int h   = blockIdx.x >> 4;   // NC=16
    const int ch  = blockIdx.x & 15;
    const size_t bstr = (size_t)NH * NT * ND;
    const float* K0 = K + (size_t)h * NT * ND + (size_t)ch * TCH * ND;
    const float* K1 = K0 + bstr;
    const float* V0 = V + (size_t)h * NT * ND + (size_t)ch * TCH * ND;
    const float* V1 = V0 + bstr;
    if (tid < 128) zacc[tid] = 0.0f;

    const int d0 = (tid & 31) << 2;  // fixed feature-quad per thread
    const int tb = tid >> 5;         // 0..7
    const int lane = tid & 63, wave = tid >> 6;
    const int mw = (wave & 1) << 6, nw = (wave >> 1) << 6;
    const int l15 = lane & 15, qd = lane >> 4;

    float zp0 = 0.f, zp1 = 0.f, zp2 = 0.f, zp3 = 0.f;
    f32x4 acc[4][4];
#pragma unroll
    for (int a = 0; a < 4; ++a)
#pragma unroll
        for (int b = 0; b < 4; ++b) acc[a][b] = (f32x4){0.f, 0.f, 0.f, 0.f};

    for (int st = 0; st < TCH / 64; ++st) {  // 4 sub-tiles of 64 t
        __syncthreads();  // protect LDS against previous iteration's readers
#pragma unroll
        for (int i = 0; i < 8; ++i) {
            int tl = tb + i * 8;  // 0..63
            size_t off = (size_t)(st * 64 + tl) * ND + d0;
            float4 a0 = *(const float4*)(K0 + off);
            float4 a1 = *(const float4*)(K1 + off);
            float4 b0 = *(const float4*)(V0 + off);
            float4 b1 = *(const float4*)(V1 + off);
            float p0 = 0.5f * (phi_f(a0.x) + phi_f(a1.x));
            float p1 = 0.5f * (phi_f(a0.y) + phi_f(a1.y));
            float p2 = 0.5f * (phi_f(a0.z) + phi_f(a1.z));
            float p3 = 0.5f * (phi_f(a0.w) + phi_f(a1.w));
            float w0 = 0.5f * (b0.x + b1.x);
            float w1 = 0.5f * (b0.y + b1.y);
            float w2 = 0.5f * (b0.z + b1.z);
            float w3 = 0.5f * (b0.w + b1.w);
            zp0 += p0; zp1 += p1; zp2 += p2; zp3 += p3;
            // transposed scatter writes (u16); bank conflicts accepted,
            // hidden under HBM latency
            Kl[(d0 + 0) * 72 + tl] = f2bf(p0);
            Kl[(d0 + 1) * 72 + tl] = f2bf(p1);
            Kl[(d0 + 2) * 72 + tl] = f2bf(p2);
            Kl[(d0 + 3) * 72 + tl] = f2bf(p3);
            Vl[(d0 + 0) * 72 + tl] = f2bf(w0);
            Vl[(d0 + 1) * 72 + tl] = f2bf(w1);
            Vl[(d0 + 2) * 72 + tl] = f2bf(w2);
            Vl[(d0 + 3) * 72 + tl] = f2bf(w3);
        }
        __syncthreads();
#pragma unroll
        for (int kk = 0; kk < 2; ++kk) {
            int k0i = kk * 32 + qd * 8;
            bf16x8 af[4], bfv[4];
#pragma unroll
            for (int im = 0; im < 4; ++im)
                af[im] = *(const bf16x8*)&Kl[(mw + im * 16 + l15) * 72 + k0i];
#pragma unroll
            for (int in = 0; in < 4; ++in)
                bfv[in] = *(const bf16x8*)&Vl[(nw + in * 16 + l15) * 72 + k0i];
#pragma unroll
            for (int im = 0; im < 4; ++im)
#pragma unroll
                for (int in = 0; in < 4; ++in)
                    acc[im][in] = __builtin_amdgcn_mfma_f32_16x16x32_bf16(
                        af[im], bfv[in], acc[im][in], 0, 0, 0);
        }
    }

    // z partial: 8 threads share each d
    atomicAdd(&zacc[d0 + 0], zp0);
    atomicAdd(&zacc[d0 + 1], zp1);
    atomicAdd(&zacc[d0 + 2], zp2);
    atomicAdd(&zacc[d0 + 3], zp3);
    __syncthreads();
    if (tid < 128) zpart[((size_t)h * NC + ch) * 128 + tid] = zacc[tid];

    float* pb = part + ((size_t)h * NC + ch) * 16384;
#pragma unroll
    for (int im = 0; im < 4; ++im)
#pragma unroll
        for (int in = 0; in < 4; ++in) {
            int col = nw + in * 16 + l15;
#pragma unroll
            for (int rg = 0; rg < 4; ++rg) {
                int row = mw + im * 16 + qd * 4 + rg;  // d index
                pb[(size_t)row * ND + col] = acc[im][in][rg];
            }
        }
}

// ---------------------------------------------------------------- k_reduce
__global__ __launch_bounds__(256) void k_reduce(const float* __restrict__ M,
                                                const float* __restrict__ z,
                                                const float* __restrict__ part,
                                                const float* __restrict__ zpart,
                                                float* __restrict__ outM,
                                                float* __restrict__ outz) {
    int idx = blockIdx.x * 256 + threadIdx.x;  // < 524288
    int h = idx >> 14, de = idx & 16383;
    float s = M[idx];
    const float* p = part + (size_t)h * NC * 16384 + de;
#pragma unroll
    for (int c = 0; c < NC; ++c) s += p[(size_t)c * 16384];
    outM[idx] = s;
    if (idx < NH * ND) {
        int hh = idx >> 7, d = idx & 127;
        float sz = z[idx];
        const float* pz = zpart + (size_t)hh * NC * 128 + d;
#pragma unroll
        for (int c = 0; c < NC; ++c) sz += pz[c * 128];
        outz[idx] = sz;
    }
}

extern "C" void kernel_launch(void* const* d_in, const int* in_sizes, int n_in,
                              void* d_out, int out_size, void* d_ws, size_t ws_size,
                              hipStream_t stream) {
    const float* Q = (const float*)d_in[0];
    const float* K = (const float*)d_in[1];
    const float* V = (const float*)d_in[2];
    const float* M = (const float*)d_in[3];
    const float* z = (const float*)d_in[4];

    float* out0 = (float*)d_out;                       // (2,32,4096,128)
    float* outM = out0 + (size_t)NB * NH * NT * ND;    // (32,128,128)
    float* outz = outM + (size_t)NH * ND * ND;         // (32,128)

    // workspace layout
    unsigned short* Mt = (unsigned short*)d_ws;                       // 1 MB
    float* part  = (float*)((char*)d_ws + (1u << 20));                // 32 MB
    float* zpart = part + (size_t)NH * NC * ND * ND;                  // 256 KB

    k_prep<<<2048, 256, 0, stream>>>(M, Mt);
    k_out<<<NB * NH * (NT / 128), 256, 0, stream>>>(Q, Mt, z, out0);
    k_upd<<<NH * NC, 256, 0, stream>>>(K, V, part, zpart);
    k_reduce<<<(NH * ND * ND) / 256, 256, 0, stream>>>(M, z, part, zpart, outM, outz);
}

// Round 2
// 425.217 us; speedup vs baseline: 1.0499x; 1.0499x over previous
//
#include <hip/hip_runtime.h>
#include <cstdint>
#include <cstddef>

// CompressiveMemory: B=2,H=32,T=4096,D=128 fp32.
// out  = phi(Q)@M / max(phi(Q)@z, eps)      (per b,h)
// Mnew = M + sum_t phiKb(t) outer Vb(t)     (phiKb/Vb are b-means)
// znew = z + sum_t phiKb(t)

typedef __bf16 bf16x8 __attribute__((ext_vector_type(8)));
typedef float  f32x4  __attribute__((ext_vector_type(4)));
typedef unsigned short us8v __attribute__((ext_vector_type(8)));

#define NB 2
#define NH 32
#define NT 4096
#define ND 128
#define NC 8            // split-K chunks for update GEMM
#define TCH (NT / NC)   // 512 t per chunk
#define NUPD (NH * NC)  // 256 update blocks (scheduled first: long poles)
#define NOUT (NB * NH * (NT / 128))  // 2048 out blocks
#define EPSF 1e-6f

__device__ __forceinline__ float phi_f(float x) {
    // elu(x)+1: x>0 -> x+1 ; x<=0 -> exp(x)
    return x > 0.0f ? x + 1.0f : __expf(x);
}

__device__ __forceinline__ unsigned short f2bf(float f) {
    union { float f; unsigned u; } c; c.f = f;
    unsigned r = c.u + 0x7FFFu + ((c.u >> 16) & 1u);  // RNE
    return (unsigned short)(r >> 16);
}

__device__ __forceinline__ bf16x8 pack8(float a0, float a1, float a2, float a3,
                                        float a4, float a5, float a6, float a7) {
    union { us8v u; bf16x8 h; } r;
    r.u[0] = f2bf(a0); r.u[1] = f2bf(a1); r.u[2] = f2bf(a2); r.u[3] = f2bf(a3);
    r.u[4] = f2bf(a4); r.u[5] = f2bf(a5); r.u[6] = f2bf(a6); r.u[7] = f2bf(a7);
    return r.h;
}

// ---------------------------------------------------------------- k_prep
// Mt[h][e][d] = bf16(M[h][d][e]). M is 2MB -> gather reads are L2-resident.
__global__ __launch_bounds__(256) void k_prep(const float* __restrict__ M,
                                              unsigned short* __restrict__ Mt) {
    int idx = blockIdx.x * 256 + threadIdx.x;  // < 32*128*128
    int h = idx >> 14, rem = idx & 16383;
    int e = rem >> 7, d = rem & 127;
    Mt[idx] = f2bf(M[(h << 14) + (d << 7) + e]);
}

// ---------------------------------------------------------------- upd body
// C[d][e] = sum_{t in chunk} phiKb[t][d] * Vb[t][e]   (k = t, MFMA)
// LDS layout: Kl/Vl [d][t] with XOR swizzle: element (d,t) stored at
// t-group (t>>3) ^ ((d>>2)&7), offset t&7, row stride 64 u16.
// -> ds_write_b128 / ds_read_b128 both near-conflict-free, 16B aligned.
__device__ __forceinline__ void upd_body(int blk, const float* __restrict__ K,
                                         const float* __restrict__ V,
                                         float* __restrict__ part,
                                         float* __restrict__ zpart,
                                         unsigned short* smem, float* zacc) {
    const int tid = threadIdx.x;
    const int h = blk >> 3, ch = blk & 7;
    unsigned short* Kl = smem;          // 128 x 64 (swizzled)
    unsigned short* Vl = smem + 8192;   // 128 x 64

    const size_t bstr = (size_t)NH * NT * ND;
    const float* K0 = K + (size_t)h * NT * ND + (size_t)ch * TCH * ND;
    const float* K1 = K0 + bstr;
    const float* V0 = V + (size_t)h * NT * ND + (size_t)ch * TCH * ND;
    const float* V1 = V0 + bstr;
    if (tid < 128) zacc[tid] = 0.0f;

    const int L = tid & 31, d0 = L << 2, tb = tid >> 5;  // thread: 4 d x 8 t
    const int lane = tid & 63, wave = tid >> 6;
    const int mw = (wave & 1) << 6, nw = (wave >> 1) << 6;
    const int l15 = lane & 15, qd = lane >> 4;
    const int grp = tb ^ (L & 7);  // swizzled t-group for writes ((d>>2)&7 == L&7)

    float zp0 = 0.f, zp1 = 0.f, zp2 = 0.f, zp3 = 0.f;
    f32x4 acc[4][4];
#pragma unroll
    for (int a = 0; a < 4; ++a)
#pragma unroll
        for (int b = 0; b < 4; ++b) acc[a][b] = (f32x4){0.f, 0.f, 0.f, 0.f};

    for (int st = 0; st < TCH / 64; ++st) {
        us8v kpu[4], vpu[4];
#pragma unroll
        for (int i = 0; i < 8; ++i) {  // 8 consecutive t rows
            size_t off = ((size_t)(st * 64 + tb * 8 + i)) * ND + d0;
            float4 a0 = *(const float4*)(K0 + off);
            float4 a1 = *(const float4*)(K1 + off);
            float4 b0 = *(const float4*)(V0 + off);
            float4 b1 = *(const float4*)(V1 + off);
            float p0 = 0.5f * (phi_f(a0.x) + phi_f(a1.x));
            float p1 = 0.5f * (phi_f(a0.y) + phi_f(a1.y));
            float p2 = 0.5f * (phi_f(a0.z) + phi_f(a1.z));
            float p3 = 0.5f * (phi_f(a0.w) + phi_f(a1.w));
            zp0 += p0; zp1 += p1; zp2 += p2; zp3 += p3;
            kpu[0][i] = f2bf(p0); kpu[1][i] = f2bf(p1);
            kpu[2][i] = f2bf(p2); kpu[3][i] = f2bf(p3);
            vpu[0][i] = f2bf(0.5f * (b0.x + b1.x));
            vpu[1][i] = f2bf(0.5f * (b0.y + b1.y));
            vpu[2][i] = f2bf(0.5f * (b0.z + b1.z));
            vpu[3][i] = f2bf(0.5f * (b0.w + b1.w));
        }
        __syncthreads();  // previous sub-tile's readers done
#pragma unroll
        for (int j = 0; j < 4; ++j) {
            *(us8v*)&Kl[(d0 + j) * 64 + grp * 8] = kpu[j];
            *(us8v*)&Vl[(d0 + j) * 64 + grp * 8] = vpu[j];
        }
        __syncthreads();
#pragma unroll
        for (int kk = 0; kk < 2; ++kk) {
            bf16x8 af[4], bv[4];
#pragma unroll
            for (int im = 0; im < 4; ++im) {
                int d = mw + im * 16 + l15;
                int sg = (kk * 4 + qd) ^ ((d >> 2) & 7);
                af[im] = *(const bf16x8*)&Kl[d * 64 + sg * 8];
            }
#pragma unroll
            for (int in = 0; in < 4; ++in) {
                int e = nw + in * 16 + l15;
                int sg = (kk * 4 + qd) ^ ((e >> 2) & 7);
                bv[in] = *(const bf16x8*)&Vl[e * 64 + sg * 8];
            }
#pragma unroll
            for (int im = 0; im < 4; ++im)
#pragma unroll
                for (int in = 0; in < 4; ++in)
                    acc[im][in] = __builtin_amdgcn_mfma_f32_16x16x32_bf16(
                        af[im], bv[in], acc[im][in], 0, 0, 0);
        }
    }

    atomicAdd(&zacc[d0 + 0], zp0);
    atomicAdd(&zacc[d0 + 1], zp1);
    atomicAdd(&zacc[d0 + 2], zp2);
    atomicAdd(&zacc[d0 + 3], zp3);
    __syncthreads();
    if (tid < 128) zpart[((size_t)h * NC + ch) * 128 + tid] = zacc[tid];

    float* pb = part + ((size_t)h * NC + ch) * 16384;
#pragma unroll
    for (int im = 0; im < 4; ++im)
#pragma unroll
        for (int in = 0; in < 4; ++in) {
            int col = nw + in * 16 + l15;
#pragma unroll
            for (int rg = 0; rg < 4; ++rg) {
                int row = mw + im * 16 + qd * 4 + rg;  // d index
                pb[(size_t)row * ND + col] = acc[im][in][rg];
            }
        }
}

// ---------------------------------------------------------------- out body
// C(128x128) = phiQ @ M per (b,h,t-tile). A-fragments straight from global
// (phi in-register); norm = phiQ . z via MFMA against z-broadcast B-frag.
// Only M^T lives in LDS (stride 136: conflict-free writes AND b128 reads).
__device__ __forceinline__ void out_body(int blk, const float* __restrict__ Q,
                                         const unsigned short* __restrict__ Mt,
                                         const float* __restrict__ z,
                                         float* __restrict__ out,
                                         unsigned short* smem) {
    const int tid = threadIdx.x;
    const int tile = blk & 31, bh = blk >> 5, h = bh & 31;
    const float* Qb = Q + ((size_t)bh * NT + (size_t)tile * 128) * ND;
    unsigned short* Bs = smem;  // [e][d], stride 136

    {
        const us8v* src = (const us8v*)(Mt + (size_t)h * 16384);
#pragma unroll
        for (int i = 0; i < 8; ++i) {
            int idx = i * 256 + tid;  // 16B chunk id
            int e = idx >> 4, d8 = idx & 15;
            *(us8v*)&Bs[e * 136 + d8 * 8] = src[idx];
        }
    }
    const int lane = tid & 63, wave = tid >> 6;
    const int mw = (wave & 1) << 6, nw = (wave >> 1) << 6;
    const int l15 = lane & 15, qd = lane >> 4;

    bf16x8 zf[4];  // z broadcast across columns -> accN col = norm(row)
#pragma unroll
    for (int kk = 0; kk < 4; ++kk) {
        const float* zp = z + h * ND + kk * 32 + qd * 8;
        float4 z0 = *(const float4*)zp;
        float4 z1 = *(const float4*)(zp + 4);
        zf[kk] = pack8(z0.x, z0.y, z0.z, z0.w, z1.x, z1.y, z1.z, z1.w);
    }
    __syncthreads();

    f32x4 acc[4][4], accN[4];
#pragma unroll
    for (int a = 0; a < 4; ++a) {
        accN[a] = (f32x4){0.f, 0.f, 0.f, 0.f};
#pragma unroll
        for (int b = 0; b < 4; ++b) acc[a][b] = (f32x4){0.f, 0.f, 0.f, 0.f};
    }

#pragma unroll
    for (int im = 0; im < 4; ++im) {
        int row = mw + im * 16 + l15;
        const float* qr = Qb + (size_t)row * ND;
        bf16x8 af[4];
#pragma unroll
        for (int kk = 0; kk < 4; ++kk) {
            const float* qp = qr + kk * 32 + qd * 8;
            float4 q0 = *(const float4*)qp;
            float4 q1 = *(const float4*)(qp + 4);
            af[kk] = pack8(phi_f(q0.x), phi_f(q0.y), phi_f(q0.z), phi_f(q0.w),
                           phi_f(q1.x), phi_f(q1.y), phi_f(q1.z), phi_f(q1.w));
        }
#pragma unroll
        for (int kk = 0; kk < 4; ++kk)
            accN[im] = __builtin_amdgcn_mfma_f32_16x16x32_bf16(
                af[kk], zf[kk], accN[im], 0, 0, 0);
#pragma unroll
        for (int in = 0; in < 4; ++in) {
            int e = nw + in * 16 + l15;
#pragma unroll
            for (int kk = 0; kk < 4; ++kk) {
                bf16x8 bv = *(const bf16x8*)&Bs[e * 136 + kk * 32 + qd * 8];
                acc[im][in] = __builtin_amdgcn_mfma_f32_16x16x32_bf16(
                    af[kk], bv, acc[im][in], 0, 0, 0);
            }
        }
    }

    float* outb = out + ((size_t)bh * NT + (size_t)tile * 128) * ND;
#pragma unroll
    for (int im = 0; im < 4; ++im) {
#pragma unroll
        for (int rg = 0; rg < 4; ++rg) {
            float inv = 1.0f / fmaxf(accN[im][rg], EPSF);
            int row = mw + im * 16 + qd * 4 + rg;
#pragma unroll
            for (int in = 0; in < 4; ++in) {
                int col = nw + in * 16 + l15;
                outb[(size_t)row * ND + col] = acc[im][in][rg] * inv;
            }
        }
    }
}

// ---------------------------------------------------------------- k_main
__global__ __launch_bounds__(256) void k_main(const float* __restrict__ Q,
                                              const float* __restrict__ K,
                                              const float* __restrict__ V,
                                              const unsigned short* __restrict__ Mt,
                                              const float* __restrict__ z,
                                              float* __restrict__ out,
                                              float* __restrict__ part,
                                              float* __restrict__ zpart) {
    __shared__ unsigned short smem[128 * 136];  // 34816 B (upd uses 32768 B)
    __shared__ float zacc[128];
    if (blockIdx.x < NUPD)
        upd_body(blockIdx.x, K, V, part, zpart, smem, zacc);
    else
        out_body(blockIdx.x - NUPD, Q, Mt, z, out, smem);
}

// ---------------------------------------------------------------- k_reduce
__global__ __launch_bounds__(256) void k_reduce(const float* __restrict__ M,
                                                const float* __restrict__ z,
                                                const float* __restrict__ part,
                                                const float* __restrict__ zpart,
                                                float* __restrict__ outM,
                                                float* __restrict__ outz) {
    int idx = blockIdx.x * 256 + threadIdx.x;  // < 524288
    int h = idx >> 14, de = idx & 16383;
    float s = M[idx];
    const float* p = part + (size_t)h * NC * 16384 + de;
#pragma unroll
    for (int c = 0; c < NC; ++c) s += p[(size_t)c * 16384];
    outM[idx] = s;
    if (idx < NH * ND) {
        int hh = idx >> 7, d = idx & 127;
        float sz = z[idx];
        const float* pz = zpart + (size_t)hh * NC * 128 + d;
#pragma unroll
        for (int c = 0; c < NC; ++c) sz += pz[c * 128];
        outz[idx] = sz;
    }
}

extern "C" void kernel_launch(void* const* d_in, const int* in_sizes, int n_in,
                              void* d_out, int out_size, void* d_ws, size_t ws_size,
                              hipStream_t stream) {
    const float* Q = (const float*)d_in[0];
    const float* K = (const float*)d_in[1];
    const float* V = (const float*)d_in[2];
    const float* M = (const float*)d_in[3];
    const float* z = (const float*)d_in[4];

    float* out0 = (float*)d_out;                     // (2,32,4096,128)
    float* outM = out0 + (size_t)NB * NH * NT * ND;  // (32,128,128)
    float* outz = outM + (size_t)NH * ND * ND;       // (32,128)

    unsigned short* Mt = (unsigned short*)d_ws;          // 1 MB
    float* part  = (float*)((char*)d_ws + (1u << 20));   // 16.8 MB
    float* zpart = part + (size_t)NH * NC * ND * ND;     // 128 KB

    k_prep<<<2048, 256, 0, stream>>>(M, Mt);
    k_main<<<NUPD + NOUT, 256, 0, stream>>>(Q, K, V, Mt, z, out0, part, zpart);
    k_reduce<<<(NH * ND * ND) / 256, 256, 0, stream>>>(M, z, part, zpart, outM, outz);
}